// Round 9
// baseline (891.199 us; speedup 1.0000x reference)
//
#include <hip/hip_runtime.h>

// ---------------------------------------------------------------------------
// GNN compound encoder, MI355X (gfx950) — round 9
// vs round 8: GEMM occupancy/balance attack. Round-8 GEMM: VALUBusy 29%,
// occupancy 8.4% (60KB wlds + 160 VGPR -> 2 waves/SIMD; 391 blocks = 1.53
// blocks/CU -> half-idle CUs). Now: FB shrunk so wlds=10-30KB, launch_bounds
// (256,4) caps VGPR at 128, grids 782/782/632 blocks (~3/CU). conv1 K halved
// 128->64 via T1 table (self-half W1b@emb[v] has 128 distinct inputs);
// k_embt deleted. DUALT epilogue fixed to use global feature index.
// Gathers/CSR/pooling unchanged from round 8.
// ---------------------------------------------------------------------------

#define NN 100000
#define NE 800000
#define NC 20000
#define NGE 320000
#define NG 256

// --------------------------- CSR build -------------------------------------
__global__ void k_count(const int* __restrict__ ei, int nE,
                        int* __restrict__ deg) {
  for (int e = blockIdx.x * blockDim.x + threadIdx.x; e < nE;
       e += gridDim.x * blockDim.x)
    atomicAdd(&deg[ei[nE + e]], 1);
}

__global__ __launch_bounds__(256) void k_scan_block(
    const int* __restrict__ deg, int n, int* __restrict__ start,
    int* __restrict__ bsum) {
  __shared__ int sh[256];
  int base = blockIdx.x * 1024 + threadIdx.x * 4;
  int v0 = (base + 0 < n) ? deg[base + 0] : 0;
  int v1 = (base + 1 < n) ? deg[base + 1] : 0;
  int v2 = (base + 2 < n) ? deg[base + 2] : 0;
  int v3 = (base + 3 < n) ? deg[base + 3] : 0;
  sh[threadIdx.x] = v0 + v1 + v2 + v3;
  __syncthreads();
  for (int off = 1; off < 256; off <<= 1) {
    int t = (threadIdx.x >= off) ? sh[threadIdx.x - off] : 0;
    __syncthreads();
    sh[threadIdx.x] += t;
    __syncthreads();
  }
  int run = (threadIdx.x == 0) ? 0 : sh[threadIdx.x - 1];
  if (base + 0 < n) start[base + 0] = run;
  run += v0;
  if (base + 1 < n) start[base + 1] = run;
  run += v1;
  if (base + 2 < n) start[base + 2] = run;
  run += v2;
  if (base + 3 < n) start[base + 3] = run;
  if (threadIdx.x == 255) bsum[blockIdx.x] = sh[255];
}

__global__ void k_scan_mid(int* __restrict__ bsum, int nb) {
  if (blockIdx.x == 0 && threadIdx.x == 0) {
    int run = 0;
    for (int i = 0; i < nb; ++i) {
      int t = bsum[i];
      bsum[i] = run;
      run += t;
    }
  }
}

__global__ void k_scan_add(int* __restrict__ start, const int* __restrict__ bsum,
                           int n) {
  int i = blockIdx.x * blockDim.x + threadIdx.x;
  if (i < n) start[i] += bsum[i >> 10];
}

__global__ void k_fill(const int* __restrict__ ei, int nE,
                       const int* __restrict__ start, int* __restrict__ cur,
                       int* __restrict__ srcl) {
  for (int e = blockIdx.x * blockDim.x + threadIdx.x; e < nE;
       e += gridDim.x * blockDim.x) {
    int t = ei[nE + e];
    int slot = start[t] + atomicAdd(&cur[t], 1);
    srcl[slot] = ei[e];
  }
}

// -------- gather-transpose: agg^T[k][node], reads node-major ---------------
template <int D, bool AFF, bool EMB>
__global__ __launch_bounds__(256) void k_gather_t(
    const float* __restrict__ src, const int* __restrict__ x,
    const int* __restrict__ start, const int* __restrict__ deg,
    const int* __restrict__ srcl, const float* __restrict__ sc,
    float* __restrict__ Zt, int n, int N) {
  constexpr int C4 = D / 4;
  constexpr int TOT = 64 * C4;
  __shared__ float zl[64][D + 1];
  const int t = threadIdx.x;
  const int nd0 = blockIdx.x * 64;
  for (int idx = t; idx < TOT; idx += 256) {
    int ndl = idx / C4, c4 = idx - ndl * C4;
    int nd = nd0 + ndl;
    float ax = 0.f, ay = 0.f, az = 0.f, aw = 0.f;
    int dg = 0;
    if (nd < n) {
      int s0 = start[nd];
      dg = deg[nd];
      for (int j = 0; j < dg; ++j) {
        int s = srcl[s0 + j];
        float4 v = EMB
            ? reinterpret_cast<const float4*>(src)[((size_t)x[s] << 4) + c4]
            : reinterpret_cast<const float4*>(src + (size_t)s * D)[c4];
        ax += v.x; ay += v.y; az += v.z; aw += v.w;
      }
    }
    if (AFF) {
      float4 sl = reinterpret_cast<const float4*>(sc)[c4];
      float4 sh = reinterpret_cast<const float4*>(sc + D)[c4];
      float fd = (float)dg;
      ax = fmaf(ax, sl.x, fd * sh.x);
      ay = fmaf(ay, sl.y, fd * sh.y);
      az = fmaf(az, sl.z, fd * sh.z);
      aw = fmaf(aw, sl.w, fd * sh.w);
    }
    zl[ndl][4 * c4 + 0] = ax;
    zl[ndl][4 * c4 + 1] = ay;
    zl[ndl][4 * c4 + 2] = az;
    zl[ndl][4 * c4 + 3] = aw;
  }
  __syncthreads();
  const int ndl = t & 63, kq = t >> 6;
  const int col = nd0 + ndl;
  if (col < n) {
    for (int k = kq; k < D; k += 4)
      Zt[(size_t)k * N + col] = zl[ndl][k];
  }
}

// -------- LDS-tiled transpose: src[n][d] -> dst[d][n] (dstride) ------------
__global__ __launch_bounds__(256) void k_transpose(
    const float* __restrict__ src, float* __restrict__ dst, int n, int d,
    int dstride) {
  __shared__ float tile[32][33];
  int c0 = blockIdx.x * 32, r0 = blockIdx.y * 32;
  int tx = threadIdx.x & 31, ty = threadIdx.x >> 5;
#pragma unroll
  for (int i = 0; i < 4; ++i) {
    int r = r0 + ty + 8 * i, c = c0 + tx;
    if (r < n && c < d) tile[ty + 8 * i][tx] = src[(size_t)r * d + c];
  }
  __syncthreads();
#pragma unroll
  for (int i = 0; i < 4; ++i) {
    int rr = c0 + ty + 8 * i, cc = r0 + tx;
    if (rr < d && cc < n) dst[(size_t)rr * dstride + cc] = tile[tx][ty + 8 * i];
  }
}

// -------- T1 table: t1[v][f] = b1[f] + sum_k w1[f][64+k]*emb[v][k] ---------
__global__ void k_t1(const float* __restrict__ w1, const float* __restrict__ b1,
                     const float* __restrict__ emb, float* __restrict__ t1) {
  int idx = blockIdx.x * 256 + threadIdx.x;
  if (idx < 128 * 80) {
    int v = idx / 80, f = idx - v * 80;
    float s = b1[f];
    const float* wr = w1 + (size_t)f * 128 + 64;
    const float* er = emb + (size_t)v * 64;
    for (int k = 0; k < 64; ++k) s = fmaf(wr[k], er[k], s);
    t1[idx] = s;
  }
}

// ------------- GEMM on transposed operands ---------------------------------
// out[g][f] = relu(sum_k Zt[k][g]*W[f][k] + base), base = bias[f] or
// T1[x[g]][f]. 256 thr: lane=t&63 -> 4 consecutive rows (block=256 rows);
// wave=t>>6 -> FT=FB/4 feats. W panel (FB rows, row-stride WS) in LDS once;
// AFFW scale-folds cols >= D1 by scW. z global->reg double-buffered,
// coalesced 1KB/wave per k; w-reads wave-uniform broadcasts.
template <int K, int WS, int D1, int FB, int FGLOB, bool AFFW, bool STATS,
          bool DUALT, bool T1M>
__global__ __launch_bounds__(256, 4) void k_gemm_t(
    const float* __restrict__ Zt, const float* __restrict__ W,
    const float* __restrict__ bias, const float* __restrict__ scW,
    const int* __restrict__ xid, const float* __restrict__ t1,
    float* __restrict__ out, float* __restrict__ outT, int tstride,
    double* __restrict__ st, int rows, int N) {
  constexpr int FT = FB / 4;
  constexpr int NCK = K / 4;
  static_assert(K % 8 == 0 && FB % 4 == 0 && D1 % 4 == 0, "shape");
  __shared__ float wlds[FB * K];

  const int t = threadIdx.x;
  const int lane = t & 63;
  const int ftb = (t >> 6) * FT;
  const int row0 = blockIdx.x * 256;
  const int fbase = blockIdx.y * FB;

  // stage W panel (+ optional BN-scale fold on k>=D1 columns)
  for (int i = t; i < FB * K / 4; i += 256) {
    int f = (4 * i) / K, k0 = (4 * i) % K;
    float4 w4 =
        *reinterpret_cast<const float4*>(&W[(size_t)(fbase + f) * WS + k0]);
    if (AFFW && k0 >= D1) {
      w4.x *= scW[k0 - D1];
      w4.y *= scW[k0 + 1 - D1];
      w4.z *= scW[k0 + 2 - D1];
      w4.w *= scW[k0 + 3 - D1];
    }
    reinterpret_cast<float4*>(wlds)[i] = w4;
  }
  float bia[FT];
  if (!T1M) {
#pragma unroll
    for (int j = 0; j < FT; ++j) bia[j] = bias[fbase + ftb + j];
  }
  __syncthreads();

  const int g0 = row0 + 4 * lane;
  const bool valid = g0 < rows;
  const float* zp = Zt + (valid ? g0 : 0);

  float acc[4][FT];
#pragma unroll
  for (int r = 0; r < 4; ++r)
#pragma unroll
    for (int j = 0; j < FT; ++j) acc[r][j] = 0.f;

  float4 a0, a1, a2, a3, b0, b1, b2, b3;

#define LOADZ(c_, q0, q1, q2, q3)                                              \
  do {                                                                         \
    const float* p_ = zp + (size_t)(4 * (c_)) * N;                             \
    q0 = *reinterpret_cast<const float4*>(p_);                                 \
    q1 = *reinterpret_cast<const float4*>(p_ + (size_t)N);                     \
    q2 = *reinterpret_cast<const float4*>(p_ + 2 * (size_t)N);                 \
    q3 = *reinterpret_cast<const float4*>(p_ + 3 * (size_t)N);                 \
  } while (0)

#define COMPZ(c_, q0, q1, q2, q3)                                              \
  do {                                                                         \
    _Pragma("unroll") for (int j = 0; j < FT; ++j) {                           \
      float4 w4 =                                                              \
          *reinterpret_cast<const float4*>(&wlds[(ftb + j) * K + 4 * (c_)]);   \
      acc[0][j] = fmaf(q0.x, w4.x, acc[0][j]);                                 \
      acc[0][j] = fmaf(q1.x, w4.y, acc[0][j]);                                 \
      acc[0][j] = fmaf(q2.x, w4.z, acc[0][j]);                                 \
      acc[0][j] = fmaf(q3.x, w4.w, acc[0][j]);                                 \
      acc[1][j] = fmaf(q0.y, w4.x, acc[1][j]);                                 \
      acc[1][j] = fmaf(q1.y, w4.y, acc[1][j]);                                 \
      acc[1][j] = fmaf(q2.y, w4.z, acc[1][j]);                                 \
      acc[1][j] = fmaf(q3.y, w4.w, acc[1][j]);                                 \
      acc[2][j] = fmaf(q0.z, w4.x, acc[2][j]);                                 \
      acc[2][j] = fmaf(q1.z, w4.y, acc[2][j]);                                 \
      acc[2][j] = fmaf(q2.z, w4.z, acc[2][j]);                                 \
      acc[2][j] = fmaf(q3.z, w4.w, acc[2][j]);                                 \
      acc[3][j] = fmaf(q0.w, w4.x, acc[3][j]);                                 \
      acc[3][j] = fmaf(q1.w, w4.y, acc[3][j]);                                 \
      acc[3][j] = fmaf(q2.w, w4.z, acc[3][j]);                                 \
      acc[3][j] = fmaf(q3.w, w4.w, acc[3][j]);                                 \
    }                                                                          \
  } while (0)

  LOADZ(0, a0, a1, a2, a3);
  for (int c = 0; c < NCK; c += 2) {     // NCK even: 16/40/48
    LOADZ(c + 1, b0, b1, b2, b3);
    COMPZ(c, a0, a1, a2, a3);
    if (c + 2 < NCK) LOADZ(c + 2, a0, a1, a2, a3);
    COMPZ(c + 1, b0, b1, b2, b3);
  }
#undef LOADZ
#undef COMPZ

  // epilogue: base (bias or T1 row) + relu
  if (T1M) {
    if (valid) {
#pragma unroll
      for (int r = 0; r < 4; ++r) {
        int xv = xid[g0 + r];
        const float* tp = t1 + (size_t)xv * FGLOB + fbase + ftb;
#pragma unroll
        for (int j = 0; j < FT; ++j) acc[r][j] += tp[j];
      }
    }
  } else {
#pragma unroll
    for (int r = 0; r < 4; ++r)
#pragma unroll
      for (int j = 0; j < FT; ++j) acc[r][j] += bia[j];
  }
#pragma unroll
  for (int r = 0; r < 4; ++r)
#pragma unroll
    for (int j = 0; j < FT; ++j) acc[r][j] = acc[r][j] > 0.f ? acc[r][j] : 0.f;

  if (valid) {
#pragma unroll
    for (int r = 0; r < 4; ++r) {
      float* op = out + (size_t)(g0 + r) * FGLOB + fbase + ftb;
#pragma unroll
      for (int j2 = 0; j2 < FT / 2; ++j2)
        *reinterpret_cast<float2*>(op + 2 * j2) =
            make_float2(acc[r][2 * j2], acc[r][2 * j2 + 1]);
    }
    if (DUALT) {
#pragma unroll
      for (int j = 0; j < FT; ++j)
        *reinterpret_cast<float4*>(
            &outT[(size_t)(fbase + ftb + j) * tstride + g0]) =
            make_float4(acc[0][j], acc[1][j], acc[2][j], acc[3][j]);
    }
  }

  if (STATS) {
#pragma unroll
    for (int j = 0; j < FT; ++j) {
      float s = 0.f, q = 0.f;
      if (valid) {
#pragma unroll
        for (int r = 0; r < 4; ++r) {
          s += acc[r][j];
          q += acc[r][j] * acc[r][j];
        }
      }
#pragma unroll
      for (int off = 1; off < 64; off <<= 1) {
        s += __shfl_xor(s, off);
        q += __shfl_xor(q, off);
      }
      if (lane == 0) {
        atomicAdd(&st[fbase + ftb + j], (double)s);
        atomicAdd(&st[FGLOB + fbase + ftb + j], (double)q);
      }
    }
  }
}

// --------------------------- BN finalize -----------------------------------
template <int D>
__global__ void k_bn_final(const double* __restrict__ st,
                           const float* __restrict__ g,
                           const float* __restrict__ be, int n,
                           float* __restrict__ sc) {
  int d = threadIdx.x;
  if (d < D) {
    double mean = st[d] / n;
    double var = st[D + d] / n - mean * mean;
    float scale = g[d] * rsqrtf((float)var + 1e-5f);
    sc[d] = scale;
    sc[D + d] = be[d] - (float)mean * scale;
  }
}

// ---- adjusted bias for W-folded affine: badj[f]=b[f]+sum_k W[f][D1+k]*sh[k]
template <int F, int K, int D1>
__global__ void k_badj(const float* __restrict__ W, const float* __restrict__ b,
                       const float* __restrict__ sc, float* __restrict__ badj) {
  int f = blockIdx.x * blockDim.x + threadIdx.x;
  if (f < F) {
    float s = b[f];
    for (int k = 0; k < K - D1; ++k)
      s += W[(size_t)f * K + D1 + k] * sc[(K - D1) + k];
    badj[f] = s;
  }
}

// ---------------- cluster max over 5 contiguous rows, fused BN apply -------
__global__ void k_cluster_max(const float* __restrict__ h2,
                              const float* __restrict__ sc,
                              float* __restrict__ y, int C) {
  int total = C * 96;
  for (int idx = blockIdx.x * blockDim.x + threadIdx.x; idx < total;
       idx += gridDim.x * blockDim.x) {
    int c = idx / 96;
    int d = idx - c * 96;
    float scale = sc[d], shift = sc[96 + d];
    const float* p = h2 + (size_t)(c * 5) * 96 + d;
    float m = fmaf(p[0], scale, shift);
    m = fmaxf(m, fmaf(p[96], scale, shift));
    m = fmaxf(m, fmaf(p[192], scale, shift));
    m = fmaxf(m, fmaf(p[288], scale, shift));
    m = fmaxf(m, fmaf(p[384], scale, shift));
    y[idx] = m;
  }
}

__global__ void k_ybatch(const int* __restrict__ batch, int* __restrict__ yb,
                         int C) {
  for (int c = blockIdx.x * blockDim.x + threadIdx.x; c < C;
       c += gridDim.x * blockDim.x) {
    int m = batch[c * 5];
    m = max(m, batch[c * 5 + 1]);
    m = max(m, batch[c * 5 + 2]);
    m = max(m, batch[c * 5 + 3]);
    m = max(m, batch[c * 5 + 4]);
    yb[c] = m;
  }
}

// --------------------------- final graph max -------------------------------
__global__ void k_graph_max(const float* __restrict__ y2,
                            const int* __restrict__ yb,
                            float* __restrict__ out, int C) {
  int total = C * 256;
  for (int idx = blockIdx.x * blockDim.x + threadIdx.x; idx < total;
       idx += gridDim.x * blockDim.x) {
    int c = idx >> 8;
    int f = idx & 255;
    atomicMax((unsigned int*)&out[(yb[c] << 8) + f],
              __float_as_uint(y2[idx]));
  }
}

// ---------------------------------------------------------------------------
extern "C" void kernel_launch(void* const* d_in, const int* in_sizes, int n_in,
                              void* d_out, int out_size, void* d_ws,
                              size_t ws_size, hipStream_t stream) {
  const int* x = (const int*)d_in[0];
  const int* ei = (const int*)d_in[1];          // [2][NE]
  const int* batch = (const int*)d_in[2];
  // d_in[3] = cluster_index (contiguous arange//5; structure used directly)
  const int* gei = (const int*)d_in[4];         // [2][NGE]
  const float* emb = (const float*)d_in[5];
  const float* w1 = (const float*)d_in[6];
  const float* b1 = (const float*)d_in[7];
  const float* g1 = (const float*)d_in[8];
  const float* be1 = (const float*)d_in[9];
  const float* w2 = (const float*)d_in[10];
  const float* b2 = (const float*)d_in[11];
  const float* g2 = (const float*)d_in[12];
  const float* be2 = (const float*)d_in[13];
  const float* wm = (const float*)d_in[14];
  const float* bm = (const float*)d_in[15];
  float* out = (float*)d_out;

  // ---- workspace overlay (floats) -----------------------------------------
  // ZA (16.0M): Z2t[160][NN]  (rows 80-159 = h1^T dual-written by conv1 GEMM)
  // ZB (12.8M): Z1t[64][NN](6.4M) -> h2(9.6M)@ZB + y(1.92M)@ZB+9.6M
  //             -> Z3t[192][NC](3.84M)@ZB
  // RC ( 8.0M): h1(8M) -> y2(5.12M)
  float* ZA = (float*)d_ws;
  float* ZB = ZA + 16000000;
  float* RC = ZB + 12800000;
  int* ip = (int*)(RC + 8000000);
  int* nd_deg = ip;            ip += NN;
  int* nd_start = ip;          ip += NN;
  int* nd_cur = ip;            ip += NN;
  int* nd_src = ip;            ip += NE;
  int* cl_deg = ip;            ip += NC;
  int* cl_start = ip;          ip += NC;
  int* cl_cur = ip;            ip += NC;
  int* cl_src = ip;            ip += NGE;
  int* yb = ip;                ip += NC;
  int* bsum = ip;              ip += 128;
  double* st = (double*)(((uintptr_t)ip + 15) & ~(uintptr_t)15);
  float* sc1 = (float*)(st + 512);
  float* sc2 = sc1 + 160;
  float* badj2 = sc2 + 192;
  float* t1 = badj2 + 128;     // [128][80]

  float* Z1t = ZB;                       // [64][NN] agg1^T
  float* Z2t = ZA;                       // [160][NN]: 0-79 agg2^T, 80-159 h1^T
  float* h1t = Z2t + (size_t)80 * NN;
  float* h1 = RC;
  float* h2 = ZB;
  float* y = ZB + 9600000;
  float* Z3t = ZB;                       // [192][NC]: 0-95 aggc^T, 96-191 y^T
  float* yT = Z3t + (size_t)96 * NC;
  float* y2 = RC;

  const int BLK = 256;
  const int GS = 2048;

  // ---- node-graph CSR (reused by both node layers)
  hipMemsetAsync(nd_deg, 0, NN * 4, stream);
  hipMemsetAsync(nd_cur, 0, NN * 4, stream);
  k_count<<<1024, BLK, 0, stream>>>(ei, NE, nd_deg);
  k_scan_block<<<(NN + 1023) / 1024, BLK, 0, stream>>>(nd_deg, NN, nd_start, bsum);
  k_scan_mid<<<1, 64, 0, stream>>>(bsum, (NN + 1023) / 1024);
  k_scan_add<<<(NN + 255) / 256, BLK, 0, stream>>>(nd_start, bsum, NN);
  k_fill<<<1024, BLK, 0, stream>>>(ei, NE, nd_start, nd_cur, nd_src);

  // ---- T1 table (conv1 self-half collapsed to 128-row lookup)
  k_t1<<<40, BLK, 0, stream>>>(w1, b1, emb, t1);

  // ---- conv1: gather (emb via x) -> Z1t; GEMM K=64 (+T1 epilogue, stats,
  //      dual-write h1^T into Z2t)
  k_gather_t<64, false, true><<<(NN + 63) / 64, BLK, 0, stream>>>(
      emb, x, nd_start, nd_deg, nd_src, nullptr, Z1t, NN, NN);
  hipMemsetAsync(st, 0, 2 * 96 * 8, stream);
  k_gemm_t<64, 128, 64, 40, 80, false, true, true, true>
      <<<dim3((NN + 255) / 256, 2), BLK, 0, stream>>>(
          Z1t, w1, nullptr, nullptr, x, t1, h1, h1t, NN, st, NN, NN);
  k_bn_final<80><<<1, 128, 0, stream>>>(st, g1, be1, NN, sc1);
  k_badj<96, 160, 80><<<1, 128, 0, stream>>>(w2, b2, sc1, badj2);

  // ---- conv2: gather-transpose (BN1 affine folded) + GEMM (W-scale fold)
  k_gather_t<80, true, false><<<(NN + 63) / 64, BLK, 0, stream>>>(
      h1, nullptr, nd_start, nd_deg, nd_src, sc1, Z2t, NN, NN);
  hipMemsetAsync(st, 0, 2 * 96 * 8, stream);
  k_gemm_t<160, 160, 80, 48, 96, true, true, false, false>
      <<<dim3((NN + 255) / 256, 2), BLK, 0, stream>>>(
          Z2t, w2, badj2, sc1, nullptr, nullptr, h2, nullptr, 0, st, NN, NN);
  k_bn_final<96><<<1, 128, 0, stream>>>(st, g2, be2, NN, sc2);

  // ---- cluster pooling (5 contiguous nodes; fused BN2 apply)
  k_cluster_max<<<GS, BLK, 0, stream>>>(h2, sc2, y, NC);
  k_ybatch<<<(NC + BLK - 1) / BLK, BLK, 0, stream>>>(batch, yb, NC);

  // ---- cluster-graph CSR
  hipMemsetAsync(cl_deg, 0, NC * 4, stream);
  hipMemsetAsync(cl_cur, 0, NC * 4, stream);
  k_count<<<512, BLK, 0, stream>>>(gei, NGE, cl_deg);
  k_scan_block<<<(NC + 1023) / 1024, BLK, 0, stream>>>(cl_deg, NC, cl_start, bsum);
  k_scan_mid<<<1, 64, 0, stream>>>(bsum, (NC + 1023) / 1024);
  k_scan_add<<<(NC + 255) / 256, BLK, 0, stream>>>(cl_start, bsum, NC);
  k_fill<<<512, BLK, 0, stream>>>(gei, NGE, cl_start, cl_cur, cl_src);

  // ---- final conv: Z3t = [aggc^T ; y^T], GEMM in 8 x 32-feature panels
  k_gather_t<96, false, false><<<(NC + 63) / 64, BLK, 0, stream>>>(
      y, nullptr, cl_start, cl_deg, cl_src, nullptr, Z3t, NC, NC);
  k_transpose<<<dim3(3, (NC + 31) / 32), BLK, 0, stream>>>(y, yT, NC, 96, NC);
  k_gemm_t<192, 192, 96, 32, 256, false, false, false, false>
      <<<dim3((NC + 255) / 256, 8), BLK, 0, stream>>>(
          Z3t, wm, bm, nullptr, nullptr, nullptr, y2, nullptr, 0, nullptr,
          NC, NC);

  // ---- graph max
  hipMemsetAsync(out, 0, (size_t)NG * 256 * 4, stream);
  k_graph_max<<<GS, BLK, 0, stream>>>(y2, yb, out, NC);
}

// Round 10
// 681.090 us; speedup vs baseline: 1.3085x; 1.3085x over previous
//
#include <hip/hip_runtime.h>

// ---------------------------------------------------------------------------
// GNN compound encoder, MI355X (gfx950) — round 10
// vs round 9: ONE change — remove the __launch_bounds__(256,4) min-waves
// clamp from k_gemm_t. Round-9 counters: VGPR_Count 64 (allocator clamped),
// WRITE_SIZE 780 MB vs 38 MB of output = register-spill scratch traffic
// through HBM (3.1 TB/s, 366 us). Natural allocation (~120 VGPR) gives
// 4 waves/SIMD spill-free with the round-9 small-FB panels (10-30 KB LDS,
// grid.y feature split, T1 table, K=64 conv1).
// ---------------------------------------------------------------------------

#define NN 100000
#define NE 800000
#define NC 20000
#define NGE 320000
#define NG 256

// --------------------------- CSR build -------------------------------------
__global__ void k_count(const int* __restrict__ ei, int nE,
                        int* __restrict__ deg) {
  for (int e = blockIdx.x * blockDim.x + threadIdx.x; e < nE;
       e += gridDim.x * blockDim.x)
    atomicAdd(&deg[ei[nE + e]], 1);
}

__global__ __launch_bounds__(256) void k_scan_block(
    const int* __restrict__ deg, int n, int* __restrict__ start,
    int* __restrict__ bsum) {
  __shared__ int sh[256];
  int base = blockIdx.x * 1024 + threadIdx.x * 4;
  int v0 = (base + 0 < n) ? deg[base + 0] : 0;
  int v1 = (base + 1 < n) ? deg[base + 1] : 0;
  int v2 = (base + 2 < n) ? deg[base + 2] : 0;
  int v3 = (base + 3 < n) ? deg[base + 3] : 0;
  sh[threadIdx.x] = v0 + v1 + v2 + v3;
  __syncthreads();
  for (int off = 1; off < 256; off <<= 1) {
    int t = (threadIdx.x >= off) ? sh[threadIdx.x - off] : 0;
    __syncthreads();
    sh[threadIdx.x] += t;
    __syncthreads();
  }
  int run = (threadIdx.x == 0) ? 0 : sh[threadIdx.x - 1];
  if (base + 0 < n) start[base + 0] = run;
  run += v0;
  if (base + 1 < n) start[base + 1] = run;
  run += v1;
  if (base + 2 < n) start[base + 2] = run;
  run += v2;
  if (base + 3 < n) start[base + 3] = run;
  if (threadIdx.x == 255) bsum[blockIdx.x] = sh[255];
}

__global__ void k_scan_mid(int* __restrict__ bsum, int nb) {
  if (blockIdx.x == 0 && threadIdx.x == 0) {
    int run = 0;
    for (int i = 0; i < nb; ++i) {
      int t = bsum[i];
      bsum[i] = run;
      run += t;
    }
  }
}

__global__ void k_scan_add(int* __restrict__ start, const int* __restrict__ bsum,
                           int n) {
  int i = blockIdx.x * blockDim.x + threadIdx.x;
  if (i < n) start[i] += bsum[i >> 10];
}

__global__ void k_fill(const int* __restrict__ ei, int nE,
                       const int* __restrict__ start, int* __restrict__ cur,
                       int* __restrict__ srcl) {
  for (int e = blockIdx.x * blockDim.x + threadIdx.x; e < nE;
       e += gridDim.x * blockDim.x) {
    int t = ei[nE + e];
    int slot = start[t] + atomicAdd(&cur[t], 1);
    srcl[slot] = ei[e];
  }
}

// -------- gather-transpose: agg^T[k][node], reads node-major ---------------
template <int D, bool AFF, bool EMB>
__global__ __launch_bounds__(256) void k_gather_t(
    const float* __restrict__ src, const int* __restrict__ x,
    const int* __restrict__ start, const int* __restrict__ deg,
    const int* __restrict__ srcl, const float* __restrict__ sc,
    float* __restrict__ Zt, int n, int N) {
  constexpr int C4 = D / 4;
  constexpr int TOT = 64 * C4;
  __shared__ float zl[64][D + 1];
  const int t = threadIdx.x;
  const int nd0 = blockIdx.x * 64;
  for (int idx = t; idx < TOT; idx += 256) {
    int ndl = idx / C4, c4 = idx - ndl * C4;
    int nd = nd0 + ndl;
    float ax = 0.f, ay = 0.f, az = 0.f, aw = 0.f;
    int dg = 0;
    if (nd < n) {
      int s0 = start[nd];
      dg = deg[nd];
      for (int j = 0; j < dg; ++j) {
        int s = srcl[s0 + j];
        float4 v = EMB
            ? reinterpret_cast<const float4*>(src)[((size_t)x[s] << 4) + c4]
            : reinterpret_cast<const float4*>(src + (size_t)s * D)[c4];
        ax += v.x; ay += v.y; az += v.z; aw += v.w;
      }
    }
    if (AFF) {
      float4 sl = reinterpret_cast<const float4*>(sc)[c4];
      float4 sh = reinterpret_cast<const float4*>(sc + D)[c4];
      float fd = (float)dg;
      ax = fmaf(ax, sl.x, fd * sh.x);
      ay = fmaf(ay, sl.y, fd * sh.y);
      az = fmaf(az, sl.z, fd * sh.z);
      aw = fmaf(aw, sl.w, fd * sh.w);
    }
    zl[ndl][4 * c4 + 0] = ax;
    zl[ndl][4 * c4 + 1] = ay;
    zl[ndl][4 * c4 + 2] = az;
    zl[ndl][4 * c4 + 3] = aw;
  }
  __syncthreads();
  const int ndl = t & 63, kq = t >> 6;
  const int col = nd0 + ndl;
  if (col < n) {
    for (int k = kq; k < D; k += 4)
      Zt[(size_t)k * N + col] = zl[ndl][k];
  }
}

// -------- LDS-tiled transpose: src[n][d] -> dst[d][n] (dstride) ------------
__global__ __launch_bounds__(256) void k_transpose(
    const float* __restrict__ src, float* __restrict__ dst, int n, int d,
    int dstride) {
  __shared__ float tile[32][33];
  int c0 = blockIdx.x * 32, r0 = blockIdx.y * 32;
  int tx = threadIdx.x & 31, ty = threadIdx.x >> 5;
#pragma unroll
  for (int i = 0; i < 4; ++i) {
    int r = r0 + ty + 8 * i, c = c0 + tx;
    if (r < n && c < d) tile[ty + 8 * i][tx] = src[(size_t)r * d + c];
  }
  __syncthreads();
#pragma unroll
  for (int i = 0; i < 4; ++i) {
    int rr = c0 + ty + 8 * i, cc = r0 + tx;
    if (rr < d && cc < n) dst[(size_t)rr * dstride + cc] = tile[tx][ty + 8 * i];
  }
}

// -------- T1 table: t1[v][f] = b1[f] + sum_k w1[f][64+k]*emb[v][k] ---------
__global__ void k_t1(const float* __restrict__ w1, const float* __restrict__ b1,
                     const float* __restrict__ emb, float* __restrict__ t1) {
  int idx = blockIdx.x * 256 + threadIdx.x;
  if (idx < 128 * 80) {
    int v = idx / 80, f = idx - v * 80;
    float s = b1[f];
    const float* wr = w1 + (size_t)f * 128 + 64;
    const float* er = emb + (size_t)v * 64;
    for (int k = 0; k < 64; ++k) s = fmaf(wr[k], er[k], s);
    t1[idx] = s;
  }
}

// ------------- GEMM on transposed operands ---------------------------------
// out[g][f] = relu(sum_k Zt[k][g]*W[f][k] + base), base = bias[f] or
// T1[x[g]][f]. 256 thr: lane=t&63 -> 4 consecutive rows (block=256 rows);
// wave=t>>6 -> FT=FB/4 feats. W panel (FB rows, row-stride WS) in LDS once;
// AFFW scale-folds cols >= D1 by scW. z global->reg double-buffered,
// coalesced 1KB/wave per k; w-reads wave-uniform broadcasts.
// NOTE: plain __launch_bounds__(256) — min-waves clamp caused 64-VGPR
// allocation + 780 MB of spill traffic in round 9.
template <int K, int WS, int D1, int FB, int FGLOB, bool AFFW, bool STATS,
          bool DUALT, bool T1M>
__global__ __launch_bounds__(256) void k_gemm_t(
    const float* __restrict__ Zt, const float* __restrict__ W,
    const float* __restrict__ bias, const float* __restrict__ scW,
    const int* __restrict__ xid, const float* __restrict__ t1,
    float* __restrict__ out, float* __restrict__ outT, int tstride,
    double* __restrict__ st, int rows, int N) {
  constexpr int FT = FB / 4;
  constexpr int NCK = K / 4;
  static_assert(K % 8 == 0 && FB % 4 == 0 && D1 % 4 == 0, "shape");
  __shared__ float wlds[FB * K];

  const int t = threadIdx.x;
  const int lane = t & 63;
  const int ftb = (t >> 6) * FT;
  const int row0 = blockIdx.x * 256;
  const int fbase = blockIdx.y * FB;

  // stage W panel (+ optional BN-scale fold on k>=D1 columns)
  for (int i = t; i < FB * K / 4; i += 256) {
    int f = (4 * i) / K, k0 = (4 * i) % K;
    float4 w4 =
        *reinterpret_cast<const float4*>(&W[(size_t)(fbase + f) * WS + k0]);
    if (AFFW && k0 >= D1) {
      w4.x *= scW[k0 - D1];
      w4.y *= scW[k0 + 1 - D1];
      w4.z *= scW[k0 + 2 - D1];
      w4.w *= scW[k0 + 3 - D1];
    }
    reinterpret_cast<float4*>(wlds)[i] = w4;
  }
  float bia[FT];
  if (!T1M) {
#pragma unroll
    for (int j = 0; j < FT; ++j) bia[j] = bias[fbase + ftb + j];
  }
  __syncthreads();

  const int g0 = row0 + 4 * lane;
  const bool valid = g0 < rows;
  const float* zp = Zt + (valid ? g0 : 0);

  float acc[4][FT];
#pragma unroll
  for (int r = 0; r < 4; ++r)
#pragma unroll
    for (int j = 0; j < FT; ++j) acc[r][j] = 0.f;

  float4 a0, a1, a2, a3, b0, b1, b2, b3;

#define LOADZ(c_, q0, q1, q2, q3)                                              \
  do {                                                                         \
    const float* p_ = zp + (size_t)(4 * (c_)) * N;                             \
    q0 = *reinterpret_cast<const float4*>(p_);                                 \
    q1 = *reinterpret_cast<const float4*>(p_ + (size_t)N);                     \
    q2 = *reinterpret_cast<const float4*>(p_ + 2 * (size_t)N);                 \
    q3 = *reinterpret_cast<const float4*>(p_ + 3 * (size_t)N);                 \
  } while (0)

#define COMPZ(c_, q0, q1, q2, q3)                                              \
  do {                                                                         \
    _Pragma("unroll") for (int j = 0; j < FT; ++j) {                           \
      float4 w4 =                                                              \
          *reinterpret_cast<const float4*>(&wlds[(ftb + j) * K + 4 * (c_)]);   \
      acc[0][j] = fmaf(q0.x, w4.x, acc[0][j]);                                 \
      acc[0][j] = fmaf(q1.x, w4.y, acc[0][j]);                                 \
      acc[0][j] = fmaf(q2.x, w4.z, acc[0][j]);                                 \
      acc[0][j] = fmaf(q3.x, w4.w, acc[0][j]);                                 \
      acc[1][j] = fmaf(q0.y, w4.x, acc[1][j]);                                 \
      acc[1][j] = fmaf(q1.y, w4.y, acc[1][j]);                                 \
      acc[1][j] = fmaf(q2.y, w4.z, acc[1][j]);                                 \
      acc[1][j] = fmaf(q3.y, w4.w, acc[1][j]);                                 \
      acc[2][j] = fmaf(q0.z, w4.x, acc[2][j]);                                 \
      acc[2][j] = fmaf(q1.z, w4.y, acc[2][j]);                                 \
      acc[2][j] = fmaf(q2.z, w4.z, acc[2][j]);                                 \
      acc[2][j] = fmaf(q3.z, w4.w, acc[2][j]);                                 \
      acc[3][j] = fmaf(q0.w, w4.x, acc[3][j]);                                 \
      acc[3][j] = fmaf(q1.w, w4.y, acc[3][j]);                                 \
      acc[3][j] = fmaf(q2.w, w4.z, acc[3][j]);                                 \
      acc[3][j] = fmaf(q3.w, w4.w, acc[3][j]);                                 \
    }                                                                          \
  } while (0)

  LOADZ(0, a0, a1, a2, a3);
  for (int c = 0; c < NCK; c += 2) {     // NCK even: 16/40/48
    LOADZ(c + 1, b0, b1, b2, b3);
    COMPZ(c, a0, a1, a2, a3);
    if (c + 2 < NCK) LOADZ(c + 2, a0, a1, a2, a3);
    COMPZ(c + 1, b0, b1, b2, b3);
  }
#undef LOADZ
#undef COMPZ

  // epilogue: base (bias or T1 row) + relu
  if (T1M) {
    if (valid) {
#pragma unroll
      for (int r = 0; r < 4; ++r) {
        int xv = xid[g0 + r];
        const float* tp = t1 + (size_t)xv * FGLOB + fbase + ftb;
#pragma unroll
        for (int j = 0; j < FT; ++j) acc[r][j] += tp[j];
      }
    }
  } else {
#pragma unroll
    for (int r = 0; r < 4; ++r)
#pragma unroll
      for (int j = 0; j < FT; ++j) acc[r][j] += bia[j];
  }
#pragma unroll
  for (int r = 0; r < 4; ++r)
#pragma unroll
    for (int j = 0; j < FT; ++j) acc[r][j] = acc[r][j] > 0.f ? acc[r][j] : 0.f;

  if (valid) {
#pragma unroll
    for (int r = 0; r < 4; ++r) {
      float* op = out + (size_t)(g0 + r) * FGLOB + fbase + ftb;
#pragma unroll
      for (int j2 = 0; j2 < FT / 2; ++j2)
        *reinterpret_cast<float2*>(op + 2 * j2) =
            make_float2(acc[r][2 * j2], acc[r][2 * j2 + 1]);
    }
    if (DUALT) {
#pragma unroll
      for (int j = 0; j < FT; ++j)
        *reinterpret_cast<float4*>(
            &outT[(size_t)(fbase + ftb + j) * tstride + g0]) =
            make_float4(acc[0][j], acc[1][j], acc[2][j], acc[3][j]);
    }
  }

  if (STATS) {
#pragma unroll
    for (int j = 0; j < FT; ++j) {
      float s = 0.f, q = 0.f;
      if (valid) {
#pragma unroll
        for (int r = 0; r < 4; ++r) {
          s += acc[r][j];
          q += acc[r][j] * acc[r][j];
        }
      }
#pragma unroll
      for (int off = 1; off < 64; off <<= 1) {
        s += __shfl_xor(s, off);
        q += __shfl_xor(q, off);
      }
      if (lane == 0) {
        atomicAdd(&st[fbase + ftb + j], (double)s);
        atomicAdd(&st[FGLOB + fbase + ftb + j], (double)q);
      }
    }
  }
}

// --------------------------- BN finalize -----------------------------------
template <int D>
__global__ void k_bn_final(const double* __restrict__ st,
                           const float* __restrict__ g,
                           const float* __restrict__ be, int n,
                           float* __restrict__ sc) {
  int d = threadIdx.x;
  if (d < D) {
    double mean = st[d] / n;
    double var = st[D + d] / n - mean * mean;
    float scale = g[d] * rsqrtf((float)var + 1e-5f);
    sc[d] = scale;
    sc[D + d] = be[d] - (float)mean * scale;
  }
}

// ---- adjusted bias for W-folded affine: badj[f]=b[f]+sum_k W[f][D1+k]*sh[k]
template <int F, int K, int D1>
__global__ void k_badj(const float* __restrict__ W, const float* __restrict__ b,
                       const float* __restrict__ sc, float* __restrict__ badj) {
  int f = blockIdx.x * blockDim.x + threadIdx.x;
  if (f < F) {
    float s = b[f];
    for (int k = 0; k < K - D1; ++k)
      s += W[(size_t)f * K + D1 + k] * sc[(K - D1) + k];
    badj[f] = s;
  }
}

// ---------------- cluster max over 5 contiguous rows, fused BN apply -------
__global__ void k_cluster_max(const float* __restrict__ h2,
                              const float* __restrict__ sc,
                              float* __restrict__ y, int C) {
  int total = C * 96;
  for (int idx = blockIdx.x * blockDim.x + threadIdx.x; idx < total;
       idx += gridDim.x * blockDim.x) {
    int c = idx / 96;
    int d = idx - c * 96;
    float scale = sc[d], shift = sc[96 + d];
    const float* p = h2 + (size_t)(c * 5) * 96 + d;
    float m = fmaf(p[0], scale, shift);
    m = fmaxf(m, fmaf(p[96], scale, shift));
    m = fmaxf(m, fmaf(p[192], scale, shift));
    m = fmaxf(m, fmaf(p[288], scale, shift));
    m = fmaxf(m, fmaf(p[384], scale, shift));
    y[idx] = m;
  }
}

__global__ void k_ybatch(const int* __restrict__ batch, int* __restrict__ yb,
                         int C) {
  for (int c = blockIdx.x * blockDim.x + threadIdx.x; c < C;
       c += gridDim.x * blockDim.x) {
    int m = batch[c * 5];
    m = max(m, batch[c * 5 + 1]);
    m = max(m, batch[c * 5 + 2]);
    m = max(m, batch[c * 5 + 3]);
    m = max(m, batch[c * 5 + 4]);
    yb[c] = m;
  }
}

// --------------------------- final graph max -------------------------------
__global__ void k_graph_max(const float* __restrict__ y2,
                            const int* __restrict__ yb,
                            float* __restrict__ out, int C) {
  int total = C * 256;
  for (int idx = blockIdx.x * blockDim.x + threadIdx.x; idx < total;
       idx += gridDim.x * blockDim.x) {
    int c = idx >> 8;
    int f = idx & 255;
    atomicMax((unsigned int*)&out[(yb[c] << 8) + f],
              __float_as_uint(y2[idx]));
  }
}

// ---------------------------------------------------------------------------
extern "C" void kernel_launch(void* const* d_in, const int* in_sizes, int n_in,
                              void* d_out, int out_size, void* d_ws,
                              size_t ws_size, hipStream_t stream) {
  const int* x = (const int*)d_in[0];
  const int* ei = (const int*)d_in[1];          // [2][NE]
  const int* batch = (const int*)d_in[2];
  // d_in[3] = cluster_index (contiguous arange//5; structure used directly)
  const int* gei = (const int*)d_in[4];         // [2][NGE]
  const float* emb = (const float*)d_in[5];
  const float* w1 = (const float*)d_in[6];
  const float* b1 = (const float*)d_in[7];
  const float* g1 = (const float*)d_in[8];
  const float* be1 = (const float*)d_in[9];
  const float* w2 = (const float*)d_in[10];
  const float* b2 = (const float*)d_in[11];
  const float* g2 = (const float*)d_in[12];
  const float* be2 = (const float*)d_in[13];
  const float* wm = (const float*)d_in[14];
  const float* bm = (const float*)d_in[15];
  float* out = (float*)d_out;

  // ---- workspace overlay (floats) -----------------------------------------
  // ZA (16.0M): Z2t[160][NN]  (rows 80-159 = h1^T dual-written by conv1 GEMM)
  // ZB (12.8M): Z1t[64][NN](6.4M) -> h2(9.6M)@ZB + y(1.92M)@ZB+9.6M
  //             -> Z3t[192][NC](3.84M)@ZB
  // RC ( 8.0M): h1(8M) -> y2(5.12M)
  float* ZA = (float*)d_ws;
  float* ZB = ZA + 16000000;
  float* RC = ZB + 12800000;
  int* ip = (int*)(RC + 8000000);
  int* nd_deg = ip;            ip += NN;
  int* nd_start = ip;          ip += NN;
  int* nd_cur = ip;            ip += NN;
  int* nd_src = ip;            ip += NE;
  int* cl_deg = ip;            ip += NC;
  int* cl_start = ip;          ip += NC;
  int* cl_cur = ip;            ip += NC;
  int* cl_src = ip;            ip += NGE;
  int* yb = ip;                ip += NC;
  int* bsum = ip;              ip += 128;
  double* st = (double*)(((uintptr_t)ip + 15) & ~(uintptr_t)15);
  float* sc1 = (float*)(st + 512);
  float* sc2 = sc1 + 160;
  float* badj2 = sc2 + 192;
  float* t1 = badj2 + 128;     // [128][80]

  float* Z1t = ZB;                       // [64][NN] agg1^T
  float* Z2t = ZA;                       // [160][NN]: 0-79 agg2^T, 80-159 h1^T
  float* h1t = Z2t + (size_t)80 * NN;
  float* h1 = RC;
  float* h2 = ZB;
  float* y = ZB + 9600000;
  float* Z3t = ZB;                       // [192][NC]: 0-95 aggc^T, 96-191 y^T
  float* yT = Z3t + (size_t)96 * NC;
  float* y2 = RC;

  const int BLK = 256;
  const int GS = 2048;

  // ---- node-graph CSR (reused by both node layers)
  hipMemsetAsync(nd_deg, 0, NN * 4, stream);
  hipMemsetAsync(nd_cur, 0, NN * 4, stream);
  k_count<<<1024, BLK, 0, stream>>>(ei, NE, nd_deg);
  k_scan_block<<<(NN + 1023) / 1024, BLK, 0, stream>>>(nd_deg, NN, nd_start, bsum);
  k_scan_mid<<<1, 64, 0, stream>>>(bsum, (NN + 1023) / 1024);
  k_scan_add<<<(NN + 255) / 256, BLK, 0, stream>>>(nd_start, bsum, NN);
  k_fill<<<1024, BLK, 0, stream>>>(ei, NE, nd_start, nd_cur, nd_src);

  // ---- T1 table (conv1 self-half collapsed to 128-row lookup)
  k_t1<<<40, BLK, 0, stream>>>(w1, b1, emb, t1);

  // ---- conv1: gather (emb via x) -> Z1t; GEMM K=64 (+T1 epilogue, stats,
  //      dual-write h1^T into Z2t)
  k_gather_t<64, false, true><<<(NN + 63) / 64, BLK, 0, stream>>>(
      emb, x, nd_start, nd_deg, nd_src, nullptr, Z1t, NN, NN);
  hipMemsetAsync(st, 0, 2 * 96 * 8, stream);
  k_gemm_t<64, 128, 64, 40, 80, false, true, true, true>
      <<<dim3((NN + 255) / 256, 2), BLK, 0, stream>>>(
          Z1t, w1, nullptr, nullptr, x, t1, h1, h1t, NN, st, NN, NN);
  k_bn_final<80><<<1, 128, 0, stream>>>(st, g1, be1, NN, sc1);
  k_badj<96, 160, 80><<<1, 128, 0, stream>>>(w2, b2, sc1, badj2);

  // ---- conv2: gather-transpose (BN1 affine folded) + GEMM (W-scale fold)
  k_gather_t<80, true, false><<<(NN + 63) / 64, BLK, 0, stream>>>(
      h1, nullptr, nd_start, nd_deg, nd_src, sc1, Z2t, NN, NN);
  hipMemsetAsync(st, 0, 2 * 96 * 8, stream);
  k_gemm_t<160, 160, 80, 48, 96, true, true, false, false>
      <<<dim3((NN + 255) / 256, 2), BLK, 0, stream>>>(
          Z2t, w2, badj2, sc1, nullptr, nullptr, h2, nullptr, 0, st, NN, NN);
  k_bn_final<96><<<1, 128, 0, stream>>>(st, g2, be2, NN, sc2);

  // ---- cluster pooling (5 contiguous nodes; fused BN2 apply)
  k_cluster_max<<<GS, BLK, 0, stream>>>(h2, sc2, y, NC);
  k_ybatch<<<(NC + BLK - 1) / BLK, BLK, 0, stream>>>(batch, yb, NC);

  // ---- cluster-graph CSR
  hipMemsetAsync(cl_deg, 0, NC * 4, stream);
  hipMemsetAsync(cl_cur, 0, NC * 4, stream);
  k_count<<<512, BLK, 0, stream>>>(gei, NGE, cl_deg);
  k_scan_block<<<(NC + 1023) / 1024, BLK, 0, stream>>>(cl_deg, NC, cl_start, bsum);
  k_scan_mid<<<1, 64, 0, stream>>>(bsum, (NC + 1023) / 1024);
  k_scan_add<<<(NC + 255) / 256, BLK, 0, stream>>>(cl_start, bsum, NC);
  k_fill<<<512, BLK, 0, stream>>>(gei, NGE, cl_start, cl_cur, cl_src);

  // ---- final conv: Z3t = [aggc^T ; y^T], GEMM in 8 x 32-feature panels
  k_gather_t<96, false, false><<<(NC + 63) / 64, BLK, 0, stream>>>(
      y, nullptr, cl_start, cl_deg, cl_src, nullptr, Z3t, NC, NC);
  k_transpose<<<dim3(3, (NC + 31) / 32), BLK, 0, stream>>>(y, yT, NC, 96, NC);
  k_gemm_t<192, 192, 96, 32, 256, false, false, false, false>
      <<<dim3((NC + 255) / 256, 8), BLK, 0, stream>>>(
          Z3t, wm, bm, nullptr, nullptr, nullptr, y2, nullptr, 0, nullptr,
          NC, NC);

  // ---- graph max
  hipMemsetAsync(out, 0, (size_t)NG * 256 * 4, stream);
  k_graph_max<<<GS, BLK, 0, stream>>>(y2, yb, out, NC);
}